// Round 6
// baseline (250.279 us; speedup 1.0000x reference)
//
#include <hip/hip_runtime.h>

// MultiHeadSelfAttention: B=2 T=2048 C=1024 H=16 D=64, causal, f32 in/out.
// R5: attn = R3 per-wave shape (4 waves x 32-row substrip-shared strips)
// + 512 single-qt blocks (2 blocks/CU), LPT order (big qt first), XCD
// clustering, double-buffered V^T (one barrier/j-tile, all threads stage).
// R4 lesson: thin strips double LDS/L1 traffic per CU — occupancy via blocks.
// einops factoring: col c of (3C) = d*48 + s*16 + h, with s: 0=Q, 1=V, 2=K.

#define BB 2
#define TT 2048
#define CC 1024
#define HH 16
#define DD 64
#define MM (BB*TT)   // 4096
#define N3 (3*CC)    // 3072
#define BH (BB*HH)   // 32

typedef unsigned short u16;
typedef unsigned int   u32;
typedef __bf16 bf16x8 __attribute__((ext_vector_type(8)));
typedef float  f32x4  __attribute__((ext_vector_type(4)));

__device__ __forceinline__ u16 f32_to_bf16(float f) {
  u32 u = __float_as_uint(f);
  return (u16)((u + 0x7fffu + ((u >> 16) & 1u)) >> 16);  // RNE
}
__device__ __forceinline__ u16 f32_to_bf16_fast(float f) {
  return (u16)((__float_as_uint(f) + 0x8000u) >> 16);    // round-half-up
}
__device__ __forceinline__ u32 pack2_bf16(float a, float b) {
  u32 ua = __float_as_uint(a) + 0x8000u;
  u32 ub = __float_as_uint(b) + 0x8000u;
  return __builtin_amdgcn_perm(ub, ua, 0x07060302);
}

// ---------------- fused cast f32 -> bf16 for x, in_w, out_w ----------------
#define N4_X  (MM * CC / 4)          // 1048576
#define N4_W  (N3 * CC / 4)          //  786432
#define N4_OW (CC * CC / 4)          //  262144
__global__ __launch_bounds__(256) void cast_all(const float* __restrict__ x,
                                                const float* __restrict__ in_w,
                                                const float* __restrict__ out_w,
                                                u16* __restrict__ xb,
                                                u16* __restrict__ wb,
                                                u16* __restrict__ owb) {
  int i = blockIdx.x * 256 + threadIdx.x;
  const float* src; u16* dst; int j;
  if (i < N4_X)            { src = x;     dst = xb;  j = i; }
  else if (i < N4_X + N4_W){ src = in_w;  dst = wb;  j = i - N4_X; }
  else                     { src = out_w; dst = owb; j = i - N4_X - N4_W; }
  float4 f = reinterpret_cast<const float4*>(src)[j];
  uint2 pk;
  pk.x = (u32)f32_to_bf16(f.x) | ((u32)f32_to_bf16(f.y) << 16);
  pk.y = (u32)f32_to_bf16(f.z) | ((u32)f32_to_bf16(f.w) << 16);
  reinterpret_cast<uint2*>(dst)[j] = pk;
}

// ---------------- tiled GEMM core: 128x128 tile, BK=64, 4 waves (verified R2) ----------------
__device__ __forceinline__ void gemm_core(const u16* __restrict__ Ag,
                                          const u16* __restrict__ Bg,
                                          int K, u16* Al, u16* Bl,
                                          int m0, int n0, f32x4 acc[4][4]) {
  const int tid = threadIdx.x, lane = tid & 63, w = tid >> 6;
  const int quad = lane >> 4, colr = lane & 15;
  const int mw = (w >> 1) * 64, nw = (w & 1) * 64;
  const int srow = lane >> 3, scol = lane & 7;
  const uint4* Al4 = reinterpret_cast<const uint4*>(Al);
  const uint4* Bl4 = reinterpret_cast<const uint4*>(Bl);
  for (int kt = 0; kt < K / 64; ++kt) {
    __syncthreads();
    #pragma unroll
    for (int ii = 0; ii < 4; ++ii) {
      int inst = w * 4 + ii;
      int row = inst * 8 + srow;
      int cs = scol ^ (row & 7);
      const u16* ga = Ag + (size_t)(m0 + row) * K + kt * 64 + cs * 8;
      const u16* gb = Bg + (size_t)(n0 + row) * K + kt * 64 + cs * 8;
      __builtin_amdgcn_global_load_lds(
          (const __attribute__((address_space(1))) void*)ga,
          (__attribute__((address_space(3))) void*)(Al + inst * 512), 16, 0, 0);
      __builtin_amdgcn_global_load_lds(
          (const __attribute__((address_space(1))) void*)gb,
          (__attribute__((address_space(3))) void*)(Bl + inst * 512), 16, 0, 0);
    }
    __syncthreads();
    #pragma unroll
    for (int ks = 0; ks < 2; ++ks) {
      bf16x8 af[4], bfr[4];
      #pragma unroll
      for (int t = 0; t < 4; ++t) {
        int mrow = mw + t * 16 + colr;
        af[t]  = __builtin_bit_cast(bf16x8, Al4[mrow * 8 + ((ks * 4 + quad) ^ (mrow & 7))]);
        int nrow = nw + t * 16 + colr;
        bfr[t] = __builtin_bit_cast(bf16x8, Bl4[nrow * 8 + ((ks * 4 + quad) ^ (nrow & 7))]);
      }
      #pragma unroll
      for (int mt = 0; mt < 4; ++mt)
        #pragma unroll
        for (int nt = 0; nt < 4; ++nt)
          acc[mt][nt] = __builtin_amdgcn_mfma_f32_16x16x32_bf16(af[mt], bfr[nt], acc[mt][nt], 0, 0, 0);
    }
  }
}

// ---------------- QKV GEMM: Y = x @ in_w^T + in_b, row-major bf16 ----------------
__global__ __launch_bounds__(256) void gemm_qkv(const u16* __restrict__ xb,
                                                const u16* __restrict__ wb,
                                                const float* __restrict__ in_b,
                                                u16* __restrict__ Y) {
  __shared__ __align__(16) u16 Al[128 * 64];
  __shared__ __align__(16) u16 Bl[128 * 64];
  const int lane = threadIdx.x & 63, w = threadIdx.x >> 6;
  const int quad = lane >> 4, colr = lane & 15;
  const int mw = (w >> 1) * 64, nw = (w & 1) * 64;
  const int m0 = blockIdx.x * 128, n0 = blockIdx.y * 128;
  f32x4 acc[4][4];
  #pragma unroll
  for (int mt = 0; mt < 4; ++mt)
    #pragma unroll
    for (int nt = 0; nt < 4; ++nt) acc[mt][nt] = (f32x4){0.f, 0.f, 0.f, 0.f};
  gemm_core(xb, wb, CC, Al, Bl, m0, n0, acc);
  float bias[4];
  #pragma unroll
  for (int nt = 0; nt < 4; ++nt) bias[nt] = in_b[n0 + nw + nt * 16 + colr];
  #pragma unroll
  for (int mt = 0; mt < 4; ++mt)
    #pragma unroll
    for (int e = 0; e < 4; ++e) {
      int row = m0 + mw + mt * 16 + quad * 4 + e;
      #pragma unroll
      for (int nt = 0; nt < 4; ++nt)
        Y[(size_t)row * N3 + n0 + nw + nt * 16 + colr] = f32_to_bf16(acc[mt][nt][e] + bias[nt]);
    }
}

// ---------------- repack Y (M x 3C) -> qkv [s][bh][t][d] ----------------
__global__ __launch_bounds__(256) void repack_qkv(const u16* __restrict__ Y,
                                                  u16* __restrict__ qkv) {
  __shared__ __align__(16) u16 Yl[N3];
  const int m = blockIdx.x, tid = threadIdx.x;
  const int b_ = m >> 11, t = m & (TT - 1);
  const uint4* Yg = reinterpret_cast<const uint4*>(Y + (size_t)m * N3);
  uint4* Yl4 = reinterpret_cast<uint4*>(Yl);
  for (int i = tid; i < N3 / 8; i += 256) Yl4[i] = Yg[i];
  __syncthreads();
  for (int it = tid; it < 768; it += 256) {
    int h = it & 15, s = (it >> 4) % 3, dg = it / 48;
    int col = s * 16 + h;
    u32 lo = (u32)Yl[(dg * 4 + 0) * 48 + col] | ((u32)Yl[(dg * 4 + 1) * 48 + col] << 16);
    u32 hi = (u32)Yl[(dg * 4 + 2) * 48 + col] | ((u32)Yl[(dg * 4 + 3) * 48 + col] << 16);
    uint2 pk; pk.x = lo; pk.y = hi;
    size_t base = (((size_t)s * BH + b_ * HH + h) * TT + t) * DD + dg * 4;
    *reinterpret_cast<uint2*>(qkv + base) = pk;
  }
}

// ---------------- MFMA flash attention ----------------
// 512 blocks of 256 threads, ONE 128-row Q-tile each -> 2 blocks/CU.
// Block index f: xcd=f&7, qtr=(f>>3)&15 (qt=15-qtr: LPT, big blocks first),
// bh=(f&7)*4+(f>>7) (4 bh per XCD -> KV L2-resident).
// Wave = 32 Q-rows (2 substrips of 16); V^T/K frags shared across substrips.
// K frags direct from global (L1). V^T double-buffered: one barrier/j-tile.
__global__ __launch_bounds__(256, 2) void attn_mfma(const u16* __restrict__ qkv,
                                                    u16* __restrict__ aout) {
  __shared__ __align__(16) u32   Vt[2][64 * 36];   // V^T bf16-pairs, dbuf
  __shared__ __align__(16) float Pl[4 * 32 * 68];  // per-wave 32x64 P strip
  const int tid  = threadIdx.x;
  const int lane = tid & 63, w = tid >> 6;
  const int quad = lane >> 4, colr = lane & 15;
  const int flat = blockIdx.x;
  const int bh = (flat & 7) * 4 + (flat >> 7);
  const int qt = 15 - ((flat >> 3) & 15);
  const int b_ = bh >> 4, h = bh & 15;
  const int i0 = qt * 128;
  const int jmax = 2 * qt + 1;

  const uint4* Qg4 = reinterpret_cast<const uint4*>(qkv + (size_t)bh * TT * DD);
  const uint4* Vg4 = reinterpret_cast<const uint4*>(qkv + ((size_t)BH + bh) * TT * DD);
  const uint4* Kg4 = reinterpret_cast<const uint4*>(qkv + ((size_t)2 * BH + bh) * TT * DD);
  const float4* Pl4 = reinterpret_cast<const float4*>(Pl);

  const int s_jp = tid & 31, s_oct = tid >> 5;   // V staging map (all 256 threads)
  const int wbase = w * (32 * 68);

  bf16x8 qa[2][2];
  #pragma unroll
  for (int u = 0; u < 2; ++u)
    #pragma unroll
    for (int ks = 0; ks < 2; ++ks)
      qa[u][ks] = __builtin_bit_cast(bf16x8,
          Qg4[(size_t)(i0 + w * 32 + u * 16 + colr) * 8 + ks * 4 + quad]);

  f32x4 oacc[2][4];
  #pragma unroll
  for (int u = 0; u < 2; ++u)
    #pragma unroll
    for (int dt = 0; dt < 4; ++dt) oacc[u][dt] = (f32x4){0.f, 0.f, 0.f, 0.f};
  float lp[2] = {0.f, 0.f};

  uint4 va = Vg4[(size_t)(2 * s_jp) * 8 + s_oct];
  uint4 vb = Vg4[(size_t)(2 * s_jp + 1) * 8 + s_oct];

  for (int jt = 0; jt <= jmax; ++jt) {
    const int j0 = jt * 64;
    u32* vtw = Vt[jt & 1];
    const uint4* vt4 = reinterpret_cast<const uint4*>(Vt[jt & 1]);

    // K frags direct from global — issue early to hide latency
    uint4 kraw[4][2];
    #pragma unroll
    for (int t4 = 0; t4 < 4; ++t4)
      #pragma unroll
      for (int ks = 0; ks < 2; ++ks)
        kraw[t4][ks] = Kg4[(size_t)(j0 + t4 * 16 + colr) * 8 + ks * 4 + quad];

    // stage V^T tile jt into buf[jt&1] (data prefetched into va/vb)
    {
      u32 aw[4] = {va.x, va.y, va.z, va.w};
      u32 bw[4] = {vb.x, vb.y, vb.z, vb.w};
      #pragma unroll
      for (int m = 0; m < 4; ++m) {
        vtw[(s_oct * 8 + 2 * m)     * 36 + s_jp] = __builtin_amdgcn_perm(bw[m], aw[m], 0x05040100);
        vtw[(s_oct * 8 + 2 * m + 1) * 36 + s_jp] = __builtin_amdgcn_perm(bw[m], aw[m], 0x07060302);
      }
    }
    if (jt < jmax) {  // prefetch next V tile
      int nj = j0 + 64;
      va = Vg4[(size_t)(nj + 2 * s_jp) * 8 + s_oct];
      vb = Vg4[(size_t)(nj + 2 * s_jp + 1) * 8 + s_oct];
    }
    __syncthreads();  // buf[jt&1] ready; prev tile's readers used other buf

    // ---- QK^T ----
    f32x4 sacc[2][4];
    #pragma unroll
    for (int u = 0; u < 2; ++u)
      #pragma unroll
      for (int t4 = 0; t4 < 4; ++t4) sacc[u][t4] = (f32x4){0.f, 0.f, 0.f, 0.f};
    #pragma unroll
    for (int t4 = 0; t4 < 4; ++t4)
      #pragma unroll
      for (int ks = 0; ks < 2; ++ks) {
        bf16x8 kb = __builtin_bit_cast(bf16x8, kraw[t4][ks]);
        #pragma unroll
        for (int u = 0; u < 2; ++u)
          sacc[u][t4] = __builtin_amdgcn_mfma_f32_16x16x32_bf16(qa[u][ks], kb, sacc[u][t4], 0, 0, 0);
      }

    // ---- exp + causal mask -> P strip (C-layout, wave-private) ----
    const bool maskt = (jt >= 2 * qt);
    const int joff = (jt - 2 * qt) * 64;
    #pragma unroll
    for (int u = 0; u < 2; ++u)
      #pragma unroll
      for (int t4 = 0; t4 < 4; ++t4)
        #pragma unroll
        for (int rg = 0; rg < 4; ++rg) {
          float p = __builtin_amdgcn_exp2f(sacc[u][t4][rg] * 0.18033688011112042f);
          if (maskt && (joff + t4 * 16 + colr > w * 32 + u * 16 + quad * 4 + rg)) p = 0.f;
          Pl[wbase + (u * 16 + quad * 4 + rg) * 68 + t4 * 16 + colr] = p;
        }

    // ---- P back in A-layout + row sums + bf16 pack ----
    bf16x8 pa[2][2];
    #pragma unroll
    for (int u = 0; u < 2; ++u)
      #pragma unroll
      for (int ks = 0; ks < 2; ++ks) {
        int b4 = (wbase + (u * 16 + colr) * 68 + ks * 32 + quad * 8) >> 2;
        float4 f0 = Pl4[b4], f1 = Pl4[b4 + 1];
        lp[u] += ((f0.x + f0.y) + (f0.z + f0.w)) + ((f1.x + f1.y) + (f1.z + f1.w));
        uint4 up;
        up.x = pack2_bf16(f0.x, f0.y); up.y = pack2_bf16(f0.z, f0.w);
        up.z = pack2_bf16(f1.x, f1.y); up.w = pack2_bf16(f1.z, f1.w);
        pa[u][ks] = __builtin_bit_cast(bf16x8, up);
      }

    // ---- PV (V frags shared across substrips) ----
    #pragma unroll
    for (int dt = 0; dt < 4; ++dt)
      #pragma unroll
      for (int ks = 0; ks < 2; ++ks) {
        bf16x8 vfr = __builtin_bit_cast(bf16x8, vt4[(dt * 16 + colr) * 9 + ks * 4 + quad]);
        #pragma unroll
        for (int u = 0; u < 2; ++u)
          oacc[u][dt] = __builtin_amdgcn_mfma_f32_16x16x32_bf16(pa[u][ks], vfr, oacc[u][dt], 0, 0, 0);
      }
  }

  // ---- epilogue ----
  #pragma unroll
  for (int u = 0; u < 2; ++u) {
    float ls = lp[u];
    ls += __shfl_xor(ls, 16);
    ls += __shfl_xor(ls, 32);
    float linv[4];
    #pragma unroll
    for (int rg = 0; rg < 4; ++rg)
      linv[rg] = 1.0f / __shfl(ls, quad * 4 + rg);
    #pragma unroll
    for (int dt = 0; dt < 4; ++dt)
      #pragma unroll
      for (int rg = 0; rg < 4; ++rg) {
        int ig = i0 + w * 32 + u * 16 + quad * 4 + rg;
        size_t off = ((size_t)(b_ * TT + ig)) * CC + h * DD + dt * 16 + colr;
        aout[off] = f32_to_bf16_fast(oacc[u][dt][rg] * linv[rg]);
      }
  }
}

// ---------------- out-proj GEMM: out = A @ out_w^T + out_b (f32 out) ----------------
__global__ __launch_bounds__(256) void gemm_out(const u16* __restrict__ ab,
                                                const u16* __restrict__ owb,
                                                const float* __restrict__ out_b,
                                                float* __restrict__ out) {
  __shared__ __align__(16) u16 Al[128 * 64];
  __shared__ __align__(16) u16 Bl[128 * 64];
  const int lane = threadIdx.x & 63, w = threadIdx.x >> 6;
  const int quad = lane >> 4, colr = lane & 15;
  const int mw = (w >> 1) * 64, nw = (w & 1) * 64;
  const int m0 = blockIdx.x * 128, n0 = blockIdx.y * 128;
  f32x4 acc[4][4];
  #pragma unroll
  for (int mt = 0; mt < 4; ++mt)
    #pragma unroll
    for (int nt = 0; nt < 4; ++nt) acc[mt][nt] = (f32x4){0.f, 0.f, 0.f, 0.f};
  gemm_core(ab, owb, CC, Al, Bl, m0, n0, acc);
  float bias[4];
  #pragma unroll
  for (int nt = 0; nt < 4; ++nt) bias[nt] = out_b[n0 + nw + nt * 16 + colr];
  #pragma unroll
  for (int mt = 0; mt < 4; ++mt)
    #pragma unroll
    for (int e = 0; e < 4; ++e) {
      int row = m0 + mw + mt * 16 + quad * 4 + e;
      #pragma unroll
      for (int nt = 0; nt < 4; ++nt)
        out[(size_t)row * CC + n0 + nw + nt * 16 + colr] = acc[mt][nt][e] + bias[nt];
    }
}

extern "C" void kernel_launch(void* const* d_in, const int* in_sizes, int n_in,
                              void* d_out, int out_size, void* d_ws, size_t ws_size,
                              hipStream_t stream) {
  const float* x     = (const float*)d_in[0];
  const float* in_w  = (const float*)d_in[1];
  const float* in_b  = (const float*)d_in[2];
  const float* out_w = (const float*)d_in[3];
  const float* out_b = (const float*)d_in[4];
  float* out = (float*)d_out;

  char* ws = (char*)d_ws;
  u16* xb  = (u16*)(ws + 0);          //  8 MB (dead after gemm_qkv)
  u16* ab  = (u16*)(ws + 0);          //  8 MB attn out (reuses xb region)
  u16* wb  = (u16*)(ws + 8388608);    //  6 MB
  u16* owb = (u16*)(ws + 14680064);   //  2 MB
  u16* Y   = (u16*)(ws + 16777216);   // 24 MB (M x 3C row-major)
  u16* qkv = (u16*)(ws + 41943040);   // 24 MB [s][bh][t][d]

  cast_all<<<dim3((N4_X + N4_W + N4_OW) / 256), 256, 0, stream>>>(x, in_w, out_w, xb, wb, owb);

  gemm_qkv<<<dim3(MM / 128, N3 / 128), 256, 0, stream>>>(xb, wb, in_b, Y);
  repack_qkv<<<dim3(MM), 256, 0, stream>>>(Y, qkv);
  attn_mfma<<<dim3(512), 256, 0, stream>>>(qkv, ab);
  gemm_out<<<dim3(MM / 128, CC / 128), 256, 0, stream>>>(ab, owb, out_b, out);
}

// Round 7
// 226.196 us; speedup vs baseline: 1.1065x; 1.1065x over previous
//
#include <hip/hip_runtime.h>

// MultiHeadSelfAttention: B=2 T=2048 C=1024 H=16 D=64, causal, f32 in/out.
// R6: attn = uniform-work pairing AND 2 blocks/CU: 128-thread blocks (2 waves
// x 32-row strips) on 64-row Q-tiles, paired (qt, 31-qt) -> 33 j-tiles/block,
// 512 blocks ALL uniform (R5 lesson: co-resident grid => balance via pairing,
// not LPT order). 32-row strips retained (R4 lesson). Dbuf V^T, XCD clusters.
// einops factoring: col c of (3C) = d*48 + s*16 + h, with s: 0=Q, 1=V, 2=K.

#define BB 2
#define TT 2048
#define CC 1024
#define HH 16
#define DD 64
#define MM (BB*TT)   // 4096
#define N3 (3*CC)    // 3072
#define BH (BB*HH)   // 32

typedef unsigned short u16;
typedef unsigned int   u32;
typedef __bf16 bf16x8 __attribute__((ext_vector_type(8)));
typedef float  f32x4  __attribute__((ext_vector_type(4)));

__device__ __forceinline__ u16 f32_to_bf16(float f) {
  u32 u = __float_as_uint(f);
  return (u16)((u + 0x7fffu + ((u >> 16) & 1u)) >> 16);  // RNE
}
__device__ __forceinline__ u16 f32_to_bf16_fast(float f) {
  return (u16)((__float_as_uint(f) + 0x8000u) >> 16);    // round-half-up
}
__device__ __forceinline__ u32 pack2_bf16(float a, float b) {
  u32 ua = __float_as_uint(a) + 0x8000u;
  u32 ub = __float_as_uint(b) + 0x8000u;
  return __builtin_amdgcn_perm(ub, ua, 0x07060302);
}

// ---------------- fused cast f32 -> bf16 for x, in_w, out_w ----------------
#define N4_X  (MM * CC / 4)          // 1048576
#define N4_W  (N3 * CC / 4)          //  786432
#define N4_OW (CC * CC / 4)          //  262144
__global__ __launch_bounds__(256) void cast_all(const float* __restrict__ x,
                                                const float* __restrict__ in_w,
                                                const float* __restrict__ out_w,
                                                u16* __restrict__ xb,
                                                u16* __restrict__ wb,
                                                u16* __restrict__ owb) {
  int i = blockIdx.x * 256 + threadIdx.x;
  const float* src; u16* dst; int j;
  if (i < N4_X)            { src = x;     dst = xb;  j = i; }
  else if (i < N4_X + N4_W){ src = in_w;  dst = wb;  j = i - N4_X; }
  else                     { src = out_w; dst = owb; j = i - N4_X - N4_W; }
  float4 f = reinterpret_cast<const float4*>(src)[j];
  uint2 pk;
  pk.x = (u32)f32_to_bf16(f.x) | ((u32)f32_to_bf16(f.y) << 16);
  pk.y = (u32)f32_to_bf16(f.z) | ((u32)f32_to_bf16(f.w) << 16);
  reinterpret_cast<uint2*>(dst)[j] = pk;
}

// ---------------- tiled GEMM core: 128x128 tile, BK=64, 4 waves (verified R2) ----------------
__device__ __forceinline__ void gemm_core(const u16* __restrict__ Ag,
                                          const u16* __restrict__ Bg,
                                          int K, u16* Al, u16* Bl,
                                          int m0, int n0, f32x4 acc[4][4]) {
  const int tid = threadIdx.x, lane = tid & 63, w = tid >> 6;
  const int quad = lane >> 4, colr = lane & 15;
  const int mw = (w >> 1) * 64, nw = (w & 1) * 64;
  const int srow = lane >> 3, scol = lane & 7;
  const uint4* Al4 = reinterpret_cast<const uint4*>(Al);
  const uint4* Bl4 = reinterpret_cast<const uint4*>(Bl);
  for (int kt = 0; kt < K / 64; ++kt) {
    __syncthreads();
    #pragma unroll
    for (int ii = 0; ii < 4; ++ii) {
      int inst = w * 4 + ii;
      int row = inst * 8 + srow;
      int cs = scol ^ (row & 7);
      const u16* ga = Ag + (size_t)(m0 + row) * K + kt * 64 + cs * 8;
      const u16* gb = Bg + (size_t)(n0 + row) * K + kt * 64 + cs * 8;
      __builtin_amdgcn_global_load_lds(
          (const __attribute__((address_space(1))) void*)ga,
          (__attribute__((address_space(3))) void*)(Al + inst * 512), 16, 0, 0);
      __builtin_amdgcn_global_load_lds(
          (const __attribute__((address_space(1))) void*)gb,
          (__attribute__((address_space(3))) void*)(Bl + inst * 512), 16, 0, 0);
    }
    __syncthreads();
    #pragma unroll
    for (int ks = 0; ks < 2; ++ks) {
      bf16x8 af[4], bfr[4];
      #pragma unroll
      for (int t = 0; t < 4; ++t) {
        int mrow = mw + t * 16 + colr;
        af[t]  = __builtin_bit_cast(bf16x8, Al4[mrow * 8 + ((ks * 4 + quad) ^ (mrow & 7))]);
        int nrow = nw + t * 16 + colr;
        bfr[t] = __builtin_bit_cast(bf16x8, Bl4[nrow * 8 + ((ks * 4 + quad) ^ (nrow & 7))]);
      }
      #pragma unroll
      for (int mt = 0; mt < 4; ++mt)
        #pragma unroll
        for (int nt = 0; nt < 4; ++nt)
          acc[mt][nt] = __builtin_amdgcn_mfma_f32_16x16x32_bf16(af[mt], bfr[nt], acc[mt][nt], 0, 0, 0);
    }
  }
}

// ---------------- QKV GEMM: Y = x @ in_w^T + in_b, row-major bf16 ----------------
__global__ __launch_bounds__(256) void gemm_qkv(const u16* __restrict__ xb,
                                                const u16* __restrict__ wb,
                                                const float* __restrict__ in_b,
                                                u16* __restrict__ Y) {
  __shared__ __align__(16) u16 Al[128 * 64];
  __shared__ __align__(16) u16 Bl[128 * 64];
  const int lane = threadIdx.x & 63, w = threadIdx.x >> 6;
  const int quad = lane >> 4, colr = lane & 15;
  const int mw = (w >> 1) * 64, nw = (w & 1) * 64;
  const int m0 = blockIdx.x * 128, n0 = blockIdx.y * 128;
  f32x4 acc[4][4];
  #pragma unroll
  for (int mt = 0; mt < 4; ++mt)
    #pragma unroll
    for (int nt = 0; nt < 4; ++nt) acc[mt][nt] = (f32x4){0.f, 0.f, 0.f, 0.f};
  gemm_core(xb, wb, CC, Al, Bl, m0, n0, acc);
  float bias[4];
  #pragma unroll
  for (int nt = 0; nt < 4; ++nt) bias[nt] = in_b[n0 + nw + nt * 16 + colr];
  #pragma unroll
  for (int mt = 0; mt < 4; ++mt)
    #pragma unroll
    for (int e = 0; e < 4; ++e) {
      int row = m0 + mw + mt * 16 + quad * 4 + e;
      #pragma unroll
      for (int nt = 0; nt < 4; ++nt)
        Y[(size_t)row * N3 + n0 + nw + nt * 16 + colr] = f32_to_bf16(acc[mt][nt][e] + bias[nt]);
    }
}

// ---------------- repack Y (M x 3C) -> qkv [s][bh][t][d] ----------------
__global__ __launch_bounds__(256) void repack_qkv(const u16* __restrict__ Y,
                                                  u16* __restrict__ qkv) {
  __shared__ __align__(16) u16 Yl[N3];
  const int m = blockIdx.x, tid = threadIdx.x;
  const int b_ = m >> 11, t = m & (TT - 1);
  const uint4* Yg = reinterpret_cast<const uint4*>(Y + (size_t)m * N3);
  uint4* Yl4 = reinterpret_cast<uint4*>(Yl);
  for (int i = tid; i < N3 / 8; i += 256) Yl4[i] = Yg[i];
  __syncthreads();
  for (int it = tid; it < 768; it += 256) {
    int h = it & 15, s = (it >> 4) % 3, dg = it / 48;
    int col = s * 16 + h;
    u32 lo = (u32)Yl[(dg * 4 + 0) * 48 + col] | ((u32)Yl[(dg * 4 + 1) * 48 + col] << 16);
    u32 hi = (u32)Yl[(dg * 4 + 2) * 48 + col] | ((u32)Yl[(dg * 4 + 3) * 48 + col] << 16);
    uint2 pk; pk.x = lo; pk.y = hi;
    size_t base = (((size_t)s * BH + b_ * HH + h) * TT + t) * DD + dg * 4;
    *reinterpret_cast<uint2*>(qkv + base) = pk;
  }
}

// ---------------- MFMA flash attention ----------------
// 512 blocks x 128 threads (2 waves). Block = paired 64-row Q-tiles (qt,31-qt)
// of one (b,h): uniform 33 j-tiles/block; 512 blocks co-resident 2/CU (LDS
// 35.8KB, cap 4) -> every CU gets exactly 66 j-tiles. Wave = 32-row strip
// (2 substrips of 16, V/K frags shared). K frags direct from global (L1).
// V^T double-buffered: one barrier per j-tile.
__global__ __launch_bounds__(128) void attn_mfma(const u16* __restrict__ qkv,
                                                 u16* __restrict__ aout) {
  __shared__ __align__(16) u32   Vt[2][64 * 36];   // V^T bf16-pairs, dbuf
  __shared__ __align__(16) float Pl[2 * 32 * 68];  // per-wave 32x64 P strip
  const int tid  = threadIdx.x;
  const int lane = tid & 63, w = tid >> 6;         // w in 0..1
  const int quad = lane >> 4, colr = lane & 15;
  const int flat = blockIdx.x;
  const int bh = (flat & 7) * 4 + (flat >> 7);     // 4 bh per XCD
  const int pr = (flat >> 3) & 15;
  const int b_ = bh >> 4, h = bh & 15;

  const uint4* Qg4 = reinterpret_cast<const uint4*>(qkv + (size_t)bh * TT * DD);
  const uint4* Vg4 = reinterpret_cast<const uint4*>(qkv + ((size_t)BH + bh) * TT * DD);
  const uint4* Kg4 = reinterpret_cast<const uint4*>(qkv + ((size_t)2 * BH + bh) * TT * DD);
  const float4* Pl4 = reinterpret_cast<const float4*>(Pl);

  const int s_jp = tid & 31, s_half = tid >> 5;    // V staging: 32 j-pairs x 4 halves
  const int wbase = w * (32 * 68);

  for (int pass = 0; pass < 2; ++pass) {
    const int qt = pass ? (31 - pr) : pr;          // 64-row tile idx, 0..31
    const int i0 = qt * 64;
    const int jmax = qt;                           // tiles 0..qt (qt+1 of them)

    bf16x8 qa[2][2];
    #pragma unroll
    for (int u = 0; u < 2; ++u)
      #pragma unroll
      for (int ks = 0; ks < 2; ++ks)
        qa[u][ks] = __builtin_bit_cast(bf16x8,
            Qg4[(size_t)(i0 + w * 32 + u * 16 + colr) * 8 + ks * 4 + quad]);

    f32x4 oacc[2][4];
    #pragma unroll
    for (int u = 0; u < 2; ++u)
      #pragma unroll
      for (int dt = 0; dt < 4; ++dt) oacc[u][dt] = (f32x4){0.f, 0.f, 0.f, 0.f};
    float lp[2] = {0.f, 0.f};

    uint4 va[2], vb[2];
    #pragma unroll
    for (int io = 0; io < 2; ++io) {
      va[io] = Vg4[(size_t)(2 * s_jp) * 8 + s_half + io * 4];
      vb[io] = Vg4[(size_t)(2 * s_jp + 1) * 8 + s_half + io * 4];
    }

    for (int jt = 0; jt <= jmax; ++jt) {
      const int j0 = jt * 64;
      u32* vtw = Vt[jt & 1];
      const uint4* vt4 = reinterpret_cast<const uint4*>(Vt[jt & 1]);

      // K frags direct from global — issue early to hide latency
      uint4 kraw[4][2];
      #pragma unroll
      for (int t4 = 0; t4 < 4; ++t4)
        #pragma unroll
        for (int ks = 0; ks < 2; ++ks)
          kraw[t4][ks] = Kg4[(size_t)(j0 + t4 * 16 + colr) * 8 + ks * 4 + quad];

      // stage V^T tile jt (each thread: 2 d-octs x 1 j-pair)
      #pragma unroll
      for (int io = 0; io < 2; ++io) {
        const int oc = s_half + io * 4;
        u32 aw[4] = {va[io].x, va[io].y, va[io].z, va[io].w};
        u32 bw[4] = {vb[io].x, vb[io].y, vb[io].z, vb[io].w};
        #pragma unroll
        for (int m = 0; m < 4; ++m) {
          vtw[(oc * 8 + 2 * m)     * 36 + s_jp] = __builtin_amdgcn_perm(bw[m], aw[m], 0x05040100);
          vtw[(oc * 8 + 2 * m + 1) * 36 + s_jp] = __builtin_amdgcn_perm(bw[m], aw[m], 0x07060302);
        }
      }
      if (jt < jmax) {  // prefetch next V tile
        int nj = j0 + 64;
        #pragma unroll
        for (int io = 0; io < 2; ++io) {
          va[io] = Vg4[(size_t)(nj + 2 * s_jp) * 8 + s_half + io * 4];
          vb[io] = Vg4[(size_t)(nj + 2 * s_jp + 1) * 8 + s_half + io * 4];
        }
      }
      __syncthreads();  // buf[jt&1] ready; prev tile's readers used other buf

      // ---- QK^T ----
      f32x4 sacc[2][4];
      #pragma unroll
      for (int u = 0; u < 2; ++u)
        #pragma unroll
        for (int t4 = 0; t4 < 4; ++t4) sacc[u][t4] = (f32x4){0.f, 0.f, 0.f, 0.f};
      #pragma unroll
      for (int t4 = 0; t4 < 4; ++t4)
        #pragma unroll
        for (int ks = 0; ks < 2; ++ks) {
          bf16x8 kb = __builtin_bit_cast(bf16x8, kraw[t4][ks]);
          #pragma unroll
          for (int u = 0; u < 2; ++u)
            sacc[u][t4] = __builtin_amdgcn_mfma_f32_16x16x32_bf16(qa[u][ks], kb, sacc[u][t4], 0, 0, 0);
        }

      // ---- exp + causal mask (only diagonal tile jt==qt) -> P strip ----
      const bool maskt = (jt == qt);
      #pragma unroll
      for (int u = 0; u < 2; ++u)
        #pragma unroll
        for (int t4 = 0; t4 < 4; ++t4)
          #pragma unroll
          for (int rg = 0; rg < 4; ++rg) {
            float p = __builtin_amdgcn_exp2f(sacc[u][t4][rg] * 0.18033688011112042f);
            if (maskt && (t4 * 16 + colr > w * 32 + u * 16 + quad * 4 + rg)) p = 0.f;
            Pl[wbase + (u * 16 + quad * 4 + rg) * 68 + t4 * 16 + colr] = p;
          }

      // ---- P back in A-layout + row sums + bf16 pack ----
      bf16x8 pa[2][2];
      #pragma unroll
      for (int u = 0; u < 2; ++u)
        #pragma unroll
        for (int ks = 0; ks < 2; ++ks) {
          int b4 = (wbase + (u * 16 + colr) * 68 + ks * 32 + quad * 8) >> 2;
          float4 f0 = Pl4[b4], f1 = Pl4[b4 + 1];
          lp[u] += ((f0.x + f0.y) + (f0.z + f0.w)) + ((f1.x + f1.y) + (f1.z + f1.w));
          uint4 up;
          up.x = pack2_bf16(f0.x, f0.y); up.y = pack2_bf16(f0.z, f0.w);
          up.z = pack2_bf16(f1.x, f1.y); up.w = pack2_bf16(f1.z, f1.w);
          pa[u][ks] = __builtin_bit_cast(bf16x8, up);
        }

      // ---- PV (V frags shared across substrips) ----
      #pragma unroll
      for (int dt = 0; dt < 4; ++dt)
        #pragma unroll
        for (int ks = 0; ks < 2; ++ks) {
          bf16x8 vfr = __builtin_bit_cast(bf16x8, vt4[(dt * 16 + colr) * 9 + ks * 4 + quad]);
          #pragma unroll
          for (int u = 0; u < 2; ++u)
            oacc[u][dt] = __builtin_amdgcn_mfma_f32_16x16x32_bf16(pa[u][ks], vfr, oacc[u][dt], 0, 0, 0);
        }
    }

    // ---- epilogue ----
    #pragma unroll
    for (int u = 0; u < 2; ++u) {
      float ls = lp[u];
      ls += __shfl_xor(ls, 16);
      ls += __shfl_xor(ls, 32);
      float linv[4];
      #pragma unroll
      for (int rg = 0; rg < 4; ++rg)
        linv[rg] = 1.0f / __shfl(ls, quad * 4 + rg);
      #pragma unroll
      for (int dt = 0; dt < 4; ++dt)
        #pragma unroll
        for (int rg = 0; rg < 4; ++rg) {
          int ig = i0 + w * 32 + u * 16 + quad * 4 + rg;
          size_t off = ((size_t)(b_ * TT + ig)) * CC + h * DD + dt * 16 + colr;
          aout[off] = f32_to_bf16_fast(oacc[u][dt][rg] * linv[rg]);
        }
    }
    __syncthreads();  // all reads of Vt done before next pass restages buf 0
  }
}

// ---------------- out-proj GEMM: out = A @ out_w^T + out_b (f32 out) ----------------
__global__ __launch_bounds__(256) void gemm_out(const u16* __restrict__ ab,
                                                const u16* __restrict__ owb,
                                                const float* __restrict__ out_b,
                                                float* __restrict__ out) {
  __shared__ __align__(16) u16 Al[128 * 64];
  __shared__ __align__(16) u16 Bl[128 * 64];
  const int lane = threadIdx.x & 63, w = threadIdx.x >> 6;
  const int quad = lane >> 4, colr = lane & 15;
  const int mw = (w >> 1) * 64, nw = (w & 1) * 64;
  const int m0 = blockIdx.x * 128, n0 = blockIdx.y * 128;
  f32x4 acc[4][4];
  #pragma unroll
  for (int mt = 0; mt < 4; ++mt)
    #pragma unroll
    for (int nt = 0; nt < 4; ++nt) acc[mt][nt] = (f32x4){0.f, 0.f, 0.f, 0.f};
  gemm_core(ab, owb, CC, Al, Bl, m0, n0, acc);
  float bias[4];
  #pragma unroll
  for (int nt = 0; nt < 4; ++nt) bias[nt] = out_b[n0 + nw + nt * 16 + colr];
  #pragma unroll
  for (int mt = 0; mt < 4; ++mt)
    #pragma unroll
    for (int e = 0; e < 4; ++e) {
      int row = m0 + mw + mt * 16 + quad * 4 + e;
      #pragma unroll
      for (int nt = 0; nt < 4; ++nt)
        out[(size_t)row * CC + n0 + nw + nt * 16 + colr] = acc[mt][nt][e] + bias[nt];
    }
}

extern "C" void kernel_launch(void* const* d_in, const int* in_sizes, int n_in,
                              void* d_out, int out_size, void* d_ws, size_t ws_size,
                              hipStream_t stream) {
  const float* x     = (const float*)d_in[0];
  const float* in_w  = (const float*)d_in[1];
  const float* in_b  = (const float*)d_in[2];
  const float* out_w = (const float*)d_in[3];
  const float* out_b = (const float*)d_in[4];
  float* out = (float*)d_out;

  char* ws = (char*)d_ws;
  u16* xb  = (u16*)(ws + 0);          //  8 MB (dead after gemm_qkv)
  u16* ab  = (u16*)(ws + 0);          //  8 MB attn out (reuses xb region)
  u16* wb  = (u16*)(ws + 8388608);    //  6 MB
  u16* owb = (u16*)(ws + 14680064);   //  2 MB
  u16* Y   = (u16*)(ws + 16777216);   // 24 MB (M x 3C row-major)
  u16* qkv = (u16*)(ws + 41943040);   // 24 MB [s][bh][t][d]

  cast_all<<<dim3((N4_X + N4_W + N4_OW) / 256), 256, 0, stream>>>(x, in_w, out_w, xb, wb, owb);

  gemm_qkv<<<dim3(MM / 128, N3 / 128), 256, 0, stream>>>(xb, wb, in_b, Y);
  repack_qkv<<<dim3(MM), 256, 0, stream>>>(Y, qkv);
  attn_mfma<<<dim3(512), 128, 0, stream>>>(qkv, ab);
  gemm_out<<<dim3(MM / 128, CC / 128), 256, 0, stream>>>(ab, owb, out_b, out);
}

// Round 8
// 223.326 us; speedup vs baseline: 1.1207x; 1.0129x over previous
//
#include <hip/hip_runtime.h>

// MultiHeadSelfAttention: B=2 T=2048 C=1024 H=16 D=64, causal, f32 in/out.
// R7: split-j attention (flash-decode): p=exp(s) has no online max, so (o,l)
// partials are additive across j-ranges. 1024 uniform blocks (16.5 j-tiles),
// 4 blocks/CU (2 waves/SIMD); partial (o,l) f32 -> dead Y region; finalize
// kernel sums+normalizes. 32-row strips / dbuf Vt / direct-global K kept.
// einops factoring: col c of (3C) = d*48 + s*16 + h, with s: 0=Q, 1=V, 2=K.

#define BB 2
#define TT 2048
#define CC 1024
#define HH 16
#define DD 64
#define MM (BB*TT)   // 4096
#define N3 (3*CC)    // 3072
#define BH (BB*HH)   // 32

typedef unsigned short u16;
typedef unsigned int   u32;
typedef __bf16 bf16x8 __attribute__((ext_vector_type(8)));
typedef float  f32x4  __attribute__((ext_vector_type(4)));

__device__ __forceinline__ u16 f32_to_bf16(float f) {
  u32 u = __float_as_uint(f);
  return (u16)((u + 0x7fffu + ((u >> 16) & 1u)) >> 16);  // RNE
}
__device__ __forceinline__ u16 f32_to_bf16_fast(float f) {
  return (u16)((__float_as_uint(f) + 0x8000u) >> 16);    // round-half-up
}
__device__ __forceinline__ u32 pack2_bf16(float a, float b) {
  u32 ua = __float_as_uint(a) + 0x8000u;
  u32 ub = __float_as_uint(b) + 0x8000u;
  return __builtin_amdgcn_perm(ub, ua, 0x07060302);
}

// ---------------- fused cast f32 -> bf16 for x, in_w, out_w ----------------
#define N4_X  (MM * CC / 4)          // 1048576
#define N4_W  (N3 * CC / 4)          //  786432
#define N4_OW (CC * CC / 4)          //  262144
__global__ __launch_bounds__(256) void cast_all(const float* __restrict__ x,
                                                const float* __restrict__ in_w,
                                                const float* __restrict__ out_w,
                                                u16* __restrict__ xb,
                                                u16* __restrict__ wb,
                                                u16* __restrict__ owb) {
  int i = blockIdx.x * 256 + threadIdx.x;
  const float* src; u16* dst; int j;
  if (i < N4_X)            { src = x;     dst = xb;  j = i; }
  else if (i < N4_X + N4_W){ src = in_w;  dst = wb;  j = i - N4_X; }
  else                     { src = out_w; dst = owb; j = i - N4_X - N4_W; }
  float4 f = reinterpret_cast<const float4*>(src)[j];
  uint2 pk;
  pk.x = (u32)f32_to_bf16(f.x) | ((u32)f32_to_bf16(f.y) << 16);
  pk.y = (u32)f32_to_bf16(f.z) | ((u32)f32_to_bf16(f.w) << 16);
  reinterpret_cast<uint2*>(dst)[j] = pk;
}

// ---------------- tiled GEMM core: 128x128 tile, BK=64, 4 waves (verified R2) ----------------
__device__ __forceinline__ void gemm_core(const u16* __restrict__ Ag,
                                          const u16* __restrict__ Bg,
                                          int K, u16* Al, u16* Bl,
                                          int m0, int n0, f32x4 acc[4][4]) {
  const int tid = threadIdx.x, lane = tid & 63, w = tid >> 6;
  const int quad = lane >> 4, colr = lane & 15;
  const int mw = (w >> 1) * 64, nw = (w & 1) * 64;
  const int srow = lane >> 3, scol = lane & 7;
  const uint4* Al4 = reinterpret_cast<const uint4*>(Al);
  const uint4* Bl4 = reinterpret_cast<const uint4*>(Bl);
  for (int kt = 0; kt < K / 64; ++kt) {
    __syncthreads();
    #pragma unroll
    for (int ii = 0; ii < 4; ++ii) {
      int inst = w * 4 + ii;
      int row = inst * 8 + srow;
      int cs = scol ^ (row & 7);
      const u16* ga = Ag + (size_t)(m0 + row) * K + kt * 64 + cs * 8;
      const u16* gb = Bg + (size_t)(n0 + row) * K + kt * 64 + cs * 8;
      __builtin_amdgcn_global_load_lds(
          (const __attribute__((address_space(1))) void*)ga,
          (__attribute__((address_space(3))) void*)(Al + inst * 512), 16, 0, 0);
      __builtin_amdgcn_global_load_lds(
          (const __attribute__((address_space(1))) void*)gb,
          (__attribute__((address_space(3))) void*)(Bl + inst * 512), 16, 0, 0);
    }
    __syncthreads();
    #pragma unroll
    for (int ks = 0; ks < 2; ++ks) {
      bf16x8 af[4], bfr[4];
      #pragma unroll
      for (int t = 0; t < 4; ++t) {
        int mrow = mw + t * 16 + colr;
        af[t]  = __builtin_bit_cast(bf16x8, Al4[mrow * 8 + ((ks * 4 + quad) ^ (mrow & 7))]);
        int nrow = nw + t * 16 + colr;
        bfr[t] = __builtin_bit_cast(bf16x8, Bl4[nrow * 8 + ((ks * 4 + quad) ^ (nrow & 7))]);
      }
      #pragma unroll
      for (int mt = 0; mt < 4; ++mt)
        #pragma unroll
        for (int nt = 0; nt < 4; ++nt)
          acc[mt][nt] = __builtin_amdgcn_mfma_f32_16x16x32_bf16(af[mt], bfr[nt], acc[mt][nt], 0, 0, 0);
    }
  }
}

// ---------------- QKV GEMM: Y = x @ in_w^T + in_b, row-major bf16 ----------------
__global__ __launch_bounds__(256) void gemm_qkv(const u16* __restrict__ xb,
                                                const u16* __restrict__ wb,
                                                const float* __restrict__ in_b,
                                                u16* __restrict__ Y) {
  __shared__ __align__(16) u16 Al[128 * 64];
  __shared__ __align__(16) u16 Bl[128 * 64];
  const int lane = threadIdx.x & 63, w = threadIdx.x >> 6;
  const int quad = lane >> 4, colr = lane & 15;
  const int mw = (w >> 1) * 64, nw = (w & 1) * 64;
  const int m0 = blockIdx.x * 128, n0 = blockIdx.y * 128;
  f32x4 acc[4][4];
  #pragma unroll
  for (int mt = 0; mt < 4; ++mt)
    #pragma unroll
    for (int nt = 0; nt < 4; ++nt) acc[mt][nt] = (f32x4){0.f, 0.f, 0.f, 0.f};
  gemm_core(xb, wb, CC, Al, Bl, m0, n0, acc);
  float bias[4];
  #pragma unroll
  for (int nt = 0; nt < 4; ++nt) bias[nt] = in_b[n0 + nw + nt * 16 + colr];
  #pragma unroll
  for (int mt = 0; mt < 4; ++mt)
    #pragma unroll
    for (int e = 0; e < 4; ++e) {
      int row = m0 + mw + mt * 16 + quad * 4 + e;
      #pragma unroll
      for (int nt = 0; nt < 4; ++nt)
        Y[(size_t)row * N3 + n0 + nw + nt * 16 + colr] = f32_to_bf16(acc[mt][nt][e] + bias[nt]);
    }
}

// ---------------- repack Y (M x 3C) -> qkv [s][bh][t][d] ----------------
__global__ __launch_bounds__(256) void repack_qkv(const u16* __restrict__ Y,
                                                  u16* __restrict__ qkv) {
  __shared__ __align__(16) u16 Yl[N3];
  const int m = blockIdx.x, tid = threadIdx.x;
  const int b_ = m >> 11, t = m & (TT - 1);
  const uint4* Yg = reinterpret_cast<const uint4*>(Y + (size_t)m * N3);
  uint4* Yl4 = reinterpret_cast<uint4*>(Yl);
  for (int i = tid; i < N3 / 8; i += 256) Yl4[i] = Yg[i];
  __syncthreads();
  for (int it = tid; it < 768; it += 256) {
    int h = it & 15, s = (it >> 4) % 3, dg = it / 48;
    int col = s * 16 + h;
    u32 lo = (u32)Yl[(dg * 4 + 0) * 48 + col] | ((u32)Yl[(dg * 4 + 1) * 48 + col] << 16);
    u32 hi = (u32)Yl[(dg * 4 + 2) * 48 + col] | ((u32)Yl[(dg * 4 + 3) * 48 + col] << 16);
    uint2 pk; pk.x = lo; pk.y = hi;
    size_t base = (((size_t)s * BH + b_ * HH + h) * TT + t) * DD + dg * 4;
    *reinterpret_cast<uint2*>(qkv + base) = pk;
  }
}

// ---------------- MFMA flash attention, split-j ----------------
// 1024 blocks x 128 threads (2 waves x 32-row strips). flat: xcd=f&7,
// hf=(f>>3)&1, pr=(f>>4)&15, bh=(f&7)*4+(f>>8) -> 4 bh per XCD.
// hf=0: [Q-tile pr, j 0..pr, FINAL] + [Q-tile 31-pr, j 0..15-pr, partial s0]
// hf=1: [Q-tile 31-pr, j 16-pr..31-pr, partial s1]   (17 vs 16 j-tiles)
// Partials (o f32 64x64, l f32 64) additive since p=exp(s) (no online max).
__global__ __launch_bounds__(128, 2) void attn_mfma(const u16* __restrict__ qkv,
                                                    u16* __restrict__ aout,
                                                    float* __restrict__ po,
                                                    float* __restrict__ pl) {
  __shared__ __align__(16) u32   Vt[2][64 * 36];   // V^T bf16-pairs, dbuf
  __shared__ __align__(16) float Pl[2 * 32 * 68];  // per-wave 32x64 P strip
  const int tid  = threadIdx.x;
  const int lane = tid & 63, w = tid >> 6;         // w in 0..1
  const int quad = lane >> 4, colr = lane & 15;
  const int flat = blockIdx.x;
  const int hf = (flat >> 3) & 1;
  const int pr = (flat >> 4) & 15;
  const int bh = (flat & 7) * 4 + (flat >> 8);
  const int b_ = bh >> 4, h = bh & 15;
  const int slot = (((bh << 4) + pr) << 1) | hf;

  const uint4* Qg4 = reinterpret_cast<const uint4*>(qkv + (size_t)bh * TT * DD);
  const uint4* Vg4 = reinterpret_cast<const uint4*>(qkv + ((size_t)BH + bh) * TT * DD);
  const uint4* Kg4 = reinterpret_cast<const uint4*>(qkv + ((size_t)2 * BH + bh) * TT * DD);
  const float4* Pl4 = reinterpret_cast<const float4*>(Pl);

  const int s_jp = tid & 31, s_half = tid >> 5;    // V staging: 32 j-pairs x 4 halves
  const int wbase = w * (32 * 68);

  const int nseg = 2 - hf;
  for (int seg = 0; seg < nseg; ++seg) {
    const bool final_out = (hf == 0) && (seg == 0);
    const int qt  = final_out ? pr : (31 - pr);
    const int jlo = (hf == 1) ? (16 - pr) : 0;
    const int jhi = (hf == 1) ? (31 - pr) : (seg == 0 ? pr : 15 - pr);
    const int i0 = qt * 64;

    bf16x8 qa[2][2];
    #pragma unroll
    for (int u = 0; u < 2; ++u)
      #pragma unroll
      for (int ks = 0; ks < 2; ++ks)
        qa[u][ks] = __builtin_bit_cast(bf16x8,
            Qg4[(size_t)(i0 + w * 32 + u * 16 + colr) * 8 + ks * 4 + quad]);

    f32x4 oacc[2][4];
    #pragma unroll
    for (int u = 0; u < 2; ++u)
      #pragma unroll
      for (int dt = 0; dt < 4; ++dt) oacc[u][dt] = (f32x4){0.f, 0.f, 0.f, 0.f};
    float lp[2] = {0.f, 0.f};

    uint4 va[2], vb[2];
    #pragma unroll
    for (int io = 0; io < 2; ++io) {
      va[io] = Vg4[(size_t)(jlo * 64 + 2 * s_jp) * 8 + s_half + io * 4];
      vb[io] = Vg4[(size_t)(jlo * 64 + 2 * s_jp + 1) * 8 + s_half + io * 4];
    }

    for (int jt = jlo; jt <= jhi; ++jt) {
      const int j0 = jt * 64;
      u32* vtw = Vt[jt & 1];
      const uint4* vt4 = reinterpret_cast<const uint4*>(Vt[jt & 1]);

      // K frags direct from global — issue early to hide latency
      uint4 kraw[4][2];
      #pragma unroll
      for (int t4 = 0; t4 < 4; ++t4)
        #pragma unroll
        for (int ks = 0; ks < 2; ++ks)
          kraw[t4][ks] = Kg4[(size_t)(j0 + t4 * 16 + colr) * 8 + ks * 4 + quad];

      // stage V^T tile jt (each thread: 2 d-octs x 1 j-pair)
      #pragma unroll
      for (int io = 0; io < 2; ++io) {
        const int oc = s_half + io * 4;
        u32 aw[4] = {va[io].x, va[io].y, va[io].z, va[io].w};
        u32 bw[4] = {vb[io].x, vb[io].y, vb[io].z, vb[io].w};
        #pragma unroll
        for (int m = 0; m < 4; ++m) {
          vtw[(oc * 8 + 2 * m)     * 36 + s_jp] = __builtin_amdgcn_perm(bw[m], aw[m], 0x05040100);
          vtw[(oc * 8 + 2 * m + 1) * 36 + s_jp] = __builtin_amdgcn_perm(bw[m], aw[m], 0x07060302);
        }
      }
      if (jt < jhi) {  // prefetch next V tile
        int nj = j0 + 64;
        #pragma unroll
        for (int io = 0; io < 2; ++io) {
          va[io] = Vg4[(size_t)(nj + 2 * s_jp) * 8 + s_half + io * 4];
          vb[io] = Vg4[(size_t)(nj + 2 * s_jp + 1) * 8 + s_half + io * 4];
        }
      }
      __syncthreads();  // buf[jt&1] ready; prev tile's readers used other buf

      // ---- QK^T ----
      f32x4 sacc[2][4];
      #pragma unroll
      for (int u = 0; u < 2; ++u)
        #pragma unroll
        for (int t4 = 0; t4 < 4; ++t4) sacc[u][t4] = (f32x4){0.f, 0.f, 0.f, 0.f};
      #pragma unroll
      for (int t4 = 0; t4 < 4; ++t4)
        #pragma unroll
        for (int ks = 0; ks < 2; ++ks) {
          bf16x8 kb = __builtin_bit_cast(bf16x8, kraw[t4][ks]);
          #pragma unroll
          for (int u = 0; u < 2; ++u)
            sacc[u][t4] = __builtin_amdgcn_mfma_f32_16x16x32_bf16(qa[u][ks], kb, sacc[u][t4], 0, 0, 0);
        }

      // ---- exp + causal mask (diagonal tile only) -> P strip ----
      const bool maskt = (jt == qt);
      #pragma unroll
      for (int u = 0; u < 2; ++u)
        #pragma unroll
        for (int t4 = 0; t4 < 4; ++t4)
          #pragma unroll
          for (int rg = 0; rg < 4; ++rg) {
            float p = __builtin_amdgcn_exp2f(sacc[u][t4][rg] * 0.18033688011112042f);
            if (maskt && (t4 * 16 + colr > w * 32 + u * 16 + quad * 4 + rg)) p = 0.f;
            Pl[wbase + (u * 16 + quad * 4 + rg) * 68 + t4 * 16 + colr] = p;
          }

      // ---- P back in A-layout + row sums + bf16 pack ----
      bf16x8 pa[2][2];
      #pragma unroll
      for (int u = 0; u < 2; ++u)
        #pragma unroll
        for (int ks = 0; ks < 2; ++ks) {
          int b4 = (wbase + (u * 16 + colr) * 68 + ks * 32 + quad * 8) >> 2;
          float4 f0 = Pl4[b4], f1 = Pl4[b4 + 1];
          lp[u] += ((f0.x + f0.y) + (f0.z + f0.w)) + ((f1.x + f1.y) + (f1.z + f1.w));
          uint4 up;
          up.x = pack2_bf16(f0.x, f0.y); up.y = pack2_bf16(f0.z, f0.w);
          up.z = pack2_bf16(f1.x, f1.y); up.w = pack2_bf16(f1.z, f1.w);
          pa[u][ks] = __builtin_bit_cast(bf16x8, up);
        }

      // ---- PV (V frags shared across substrips) ----
      #pragma unroll
      for (int dt = 0; dt < 4; ++dt)
        #pragma unroll
        for (int ks = 0; ks < 2; ++ks) {
          bf16x8 vfr = __builtin_bit_cast(bf16x8, vt4[(dt * 16 + colr) * 9 + ks * 4 + quad]);
          #pragma unroll
          for (int u = 0; u < 2; ++u)
            oacc[u][dt] = __builtin_amdgcn_mfma_f32_16x16x32_bf16(pa[u][ks], vfr, oacc[u][dt], 0, 0, 0);
        }
    }

    // ---- epilogue ----
    #pragma unroll
    for (int u = 0; u < 2; ++u) {
      float ls = lp[u];
      ls += __shfl_xor(ls, 16);
      ls += __shfl_xor(ls, 32);   // lanes 0..15 hold row sums of substrip rows
      if (final_out) {
        float linv[4];
        #pragma unroll
        for (int rg = 0; rg < 4; ++rg)
          linv[rg] = 1.0f / __shfl(ls, quad * 4 + rg);
        #pragma unroll
        for (int dt = 0; dt < 4; ++dt)
          #pragma unroll
          for (int rg = 0; rg < 4; ++rg) {
            int ig = i0 + w * 32 + u * 16 + quad * 4 + rg;
            size_t off = ((size_t)(b_ * TT + ig)) * CC + h * DD + dt * 16 + colr;
            aout[off] = f32_to_bf16_fast(oacc[u][dt][rg] * linv[rg]);
          }
      } else {
        float* ob = po + (size_t)slot * 4096;
        #pragma unroll
        for (int dt = 0; dt < 4; ++dt)
          #pragma unroll
          for (int rg = 0; rg < 4; ++rg)
            ob[(w * 32 + u * 16 + quad * 4 + rg) * 64 + dt * 16 + colr] = oacc[u][dt][rg];
        if (lane < 16) pl[slot * 64 + w * 32 + u * 16 + lane] = ls;
      }
    }
    __syncthreads();  // all reads of Vt done before next segment restages
  }
}

// ---------------- finalize split Q-tiles (qt 16..31): o = (o0+o1)/(l0+l1) ----------------
__global__ __launch_bounds__(256) void attn_finalize(const float* __restrict__ po,
                                                     const float* __restrict__ pl,
                                                     u16* __restrict__ aout) {
  const int blk = blockIdx.x;       // bh*16 + pr
  const int bh = blk >> 4, pr = blk & 15;
  const int qt = 31 - pr;
  const int b_ = bh >> 4, h = bh & 15;
  const int t = threadIdx.x;
  const int r = t >> 2, dq = t & 3;
  const size_t s0 = (size_t)blk * 2, s1 = s0 + 1;
  const float4* o0 = reinterpret_cast<const float4*>(po + s0 * 4096 + r * 64 + dq * 16);
  const float4* o1 = reinterpret_cast<const float4*>(po + s1 * 4096 + r * 64 + dq * 16);
  float inv = 1.0f / (pl[s0 * 64 + r] + pl[s1 * 64 + r]);
  int ig = qt * 64 + r;
  u16* dst = aout + ((size_t)(b_ * TT + ig)) * CC + h * DD + dq * 16;
  #pragma unroll
  for (int c = 0; c < 4; ++c) {
    float4 a = o0[c], b = o1[c];
    uint2 pk;
    pk.x = pack2_bf16((a.x + b.x) * inv, (a.y + b.y) * inv);
    pk.y = pack2_bf16((a.z + b.z) * inv, (a.w + b.w) * inv);
    *reinterpret_cast<uint2*>(dst + c * 4) = pk;
  }
}

// ---------------- out-proj GEMM: out = A @ out_w^T + out_b (f32 out) ----------------
__global__ __launch_bounds__(256) void gemm_out(const u16* __restrict__ ab,
                                                const u16* __restrict__ owb,
                                                const float* __restrict__ out_b,
                                                float* __restrict__ out) {
  __shared__ __align__(16) u16 Al[128 * 64];
  __shared__ __align__(16) u16 Bl[128 * 64];
  const int lane = threadIdx.x & 63, w = threadIdx.x >> 6;
  const int quad = lane >> 4, colr = lane & 15;
  const int mw = (w >> 1) * 64, nw = (w & 1) * 64;
  const int m0 = blockIdx.x * 128, n0 = blockIdx.y * 128;
  f32x4 acc[4][4];
  #pragma unroll
  for (int mt = 0; mt < 4; ++mt)
    #pragma unroll
    for (int nt = 0; nt < 4; ++nt) acc[mt][nt] = (f32x4){0.f, 0.f, 0.f, 0.f};
  gemm_core(ab, owb, CC, Al, Bl, m0, n0, acc);
  float bias[4];
  #pragma unroll
  for (int nt = 0; nt < 4; ++nt) bias[nt] = out_b[n0 + nw + nt * 16 + colr];
  #pragma unroll
  for (int mt = 0; mt < 4; ++mt)
    #pragma unroll
    for (int e = 0; e < 4; ++e) {
      int row = m0 + mw + mt * 16 + quad * 4 + e;
      #pragma unroll
      for (int nt = 0; nt < 4; ++nt)
        out[(size_t)row * CC + n0 + nw + nt * 16 + colr] = acc[mt][nt][e] + bias[nt];
    }
}

extern "C" void kernel_launch(void* const* d_in, const int* in_sizes, int n_in,
                              void* d_out, int out_size, void* d_ws, size_t ws_size,
                              hipStream_t stream) {
  const float* x     = (const float*)d_in[0];
  const float* in_w  = (const float*)d_in[1];
  const float* in_b  = (const float*)d_in[2];
  const float* out_w = (const float*)d_in[3];
  const float* out_b = (const float*)d_in[4];
  float* out = (float*)d_out;

  char* ws = (char*)d_ws;
  u16* xb  = (u16*)(ws + 0);          //  8 MB (dead after gemm_qkv)
  u16* ab  = (u16*)(ws + 0);          //  8 MB attn out (reuses xb region)
  u16* wb  = (u16*)(ws + 8388608);    //  6 MB
  u16* owb = (u16*)(ws + 14680064);   //  2 MB
  u16* Y   = (u16*)(ws + 16777216);   // 24 MB (M x 3C row-major; dead after repack)
  float* po = (float*)(ws + 16777216);          // 16.78 MB partial o (reuses Y)
  float* pl = (float*)(ws + 16777216 + 16777216); // 256 KB partial l
  u16* qkv = (u16*)(ws + 41943040);   // 24 MB [s][bh][t][d]

  cast_all<<<dim3((N4_X + N4_W + N4_OW) / 256), 256, 0, stream>>>(x, in_w, out_w, xb, wb, owb);

  gemm_qkv<<<dim3(MM / 128, N3 / 128), 256, 0, stream>>>(xb, wb, in_b, Y);
  repack_qkv<<<dim3(MM), 256, 0, stream>>>(Y, qkv);
  attn_mfma<<<dim3(1024), 128, 0, stream>>>(qkv, ab, po, pl);
  attn_finalize<<<dim3(512), 256, 0, stream>>>(po, pl, ab);
  gemm_out<<<dim3(MM / 128, CC / 128), 256, 0, stream>>>(ab, owb, out_b, out);
}